// Round 20
// baseline (796.215 us; speedup 1.0000x reference)
//
#include <hip/hip_runtime.h>
#include <hip/hip_bf16.h>

#define DEV __device__ __forceinline__

using bf16 = __hip_bfloat16;
typedef __attribute__((ext_vector_type(8))) short short8v;  // 8 bf16 = 4 VGPRs
typedef __attribute__((ext_vector_type(4))) float f32x4;

constexpr int Bq = 16, Tq = 1024, Eq = 1024, Gq = 4, Nq = 8, Dq = 128, Vq = 2048;
constexpr int M1 = Bq * Tq;        // 16384
constexpr int N1q = Gq * Nq * Dq;  // 4096
constexpr int K1 = Eq;             // 1024
constexpr int K2 = Nq * Dq;        // 1024
constexpr int N2 = Vq;             // 2048

DEV unsigned short bfu(float x) {
  union { bf16 h; unsigned short u; } cv;
  cv.h = __float2bfloat16(x);
  return cv.u;
}

DEV float rcp_(float x) { return __builtin_amdgcn_rcpf(x); }
DEV float sigm(float x) { return rcp_(1.0f + __expf(-x)); }
DEV float tanh_(float x) { return fmaf(2.0f, rcp_(1.0f + __expf(-2.0f * x)), -1.0f); }

// async global->LDS, 16B per lane; LDS dest is wave-uniform base + lane*16
#define GLD16(gp, lp)                                                       \
  __builtin_amdgcn_global_load_lds(                                        \
      (const __attribute__((address_space(1))) void*)(gp),                 \
      (__attribute__((address_space(3))) void*)(lp), 16, 0, 0)

#define SBAR0() __builtin_amdgcn_sched_barrier(0)
#define RAWBAR()                                                            \
  do { SBAR0(); __builtin_amdgcn_s_barrier(); SBAR0(); } while (0)
#define VMW6() asm volatile("s_waitcnt vmcnt(6)" ::: "memory")
#define VMW3() asm volatile("s_waitcnt vmcnt(3)" ::: "memory")
#define VMW0() asm volatile("s_waitcnt vmcnt(0)" ::: "memory")

// ---------------------------------------------------------------------------
// Prep kernels
// ---------------------------------------------------------------------------
__global__ __launch_bounds__(256) void cast_f32_bf16(const float* __restrict__ s,
                                                     bf16* __restrict__ d, int n4) {
  const int i = blockIdx.x * 256 + threadIdx.x;
  if (i >= n4) return;
  const float4 v = ((const float4*)s)[i];
  ushort4 u;
  u.x = bfu(v.x); u.y = bfu(v.y); u.z = bfu(v.z); u.w = bfu(v.w);
  ((ushort4*)d)[i] = u;
}

// W_in[k][c] f32 (c = g*1024+n*128+dd) -> WiT_perm[n*512 + dd*4 + g][k] bf16.
__global__ __launch_bounds__(256) void transpose_cast_perm(const float* __restrict__ s,
                                                           bf16* __restrict__ d,
                                                           int SK, int SN) {
  __shared__ float t[32][33];
  const int n0 = blockIdx.x * 32, k0 = blockIdx.y * 32;
  const int tx = threadIdx.x & 31, ty = threadIdx.x >> 5;  // ty: 0..7
#pragma unroll
  for (int i = 0; i < 32; i += 8)
    t[ty + i][tx] = s[(size_t)(k0 + ty + i) * SN + n0 + tx];
  __syncthreads();
#pragma unroll
  for (int i = 0; i < 32; i += 8) {
    const int c = n0 + ty + i;
    const int g = c >> 10, n = (c >> 7) & 7, dd = c & 127;
    const int rp = n * 512 + dd * 4 + g;
    d[(size_t)rp * SK + k0 + tx] = __float2bfloat16(t[tx][ty + i]);
  }
}

__global__ __launch_bounds__(256) void zero_flags(unsigned int* __restrict__ f) {
  f[blockIdx.x * 256 + threadIdx.x] = 0u;
}

// ---------------------------------------------------------------------------
// Standalone bf16 MFMA GEMM (m97 structure) for the output projection:
// C[M,N] f32 = A[M,K] @ Bt[N,K]^T + bias.  (multi-WG/CU co-residency hides
// the per-K-step barrier drain — do NOT fold this into a 1-WG/CU kernel.)
// ---------------------------------------------------------------------------
__global__ __launch_bounds__(256) void gemm_out(const bf16* __restrict__ A,
                                                const bf16* __restrict__ Bt,
                                                float* __restrict__ C,
                                                const float* __restrict__ bp,
                                                int K, int N) {
  __shared__ bf16 As[128 * 32];
  __shared__ bf16 Bs[128 * 32];
  const int m0 = blockIdx.y * 128, n0 = blockIdx.x * 128;
  const int tid = threadIdx.x;
  const int lane = tid & 63, w = tid >> 6;
  const int wm = w >> 1, wn = w & 1;

  const int srow = lane >> 2, scol = (lane & 3) * 8;
  const int ca = w * 2;
  const bf16* Ag0 = A + (size_t)(m0 + ca * 16 + srow) * K + scol;
  const bf16* Ag1 = Ag0 + (size_t)16 * K;
  const bf16* Bg0 = Bt + (size_t)(n0 + ca * 16 + srow) * K + scol;
  const bf16* Bg1 = Bg0 + (size_t)16 * K;
  bf16* Al0 = As + ca * 512;
  bf16* Al1 = Al0 + 512;
  bf16* Bl0 = Bs + ca * 512;
  bf16* Bl1 = Bl0 + 512;

  f32x4 acc[4][4] = {};
  const int rr = lane & 15;
  const int kb = (lane >> 4) * 8;

  for (int k0 = 0; k0 < K; k0 += 32) {
    GLD16(Ag0 + k0, Al0);
    GLD16(Ag1 + k0, Al1);
    GLD16(Bg0 + k0, Bl0);
    GLD16(Bg1 + k0, Bl1);
    __syncthreads();
    short8v af[4], bfr[4];
#pragma unroll
    for (int i = 0; i < 4; ++i) {
      af[i]  = *(const short8v*)&As[(wm * 64 + i * 16 + rr) * 32 + kb];
      bfr[i] = *(const short8v*)&Bs[(wn * 64 + i * 16 + rr) * 32 + kb];
    }
#pragma unroll
    for (int i = 0; i < 4; ++i)
#pragma unroll
      for (int j = 0; j < 4; ++j)
        acc[i][j] = __builtin_amdgcn_mfma_f32_16x16x32_bf16(af[i], bfr[j], acc[i][j], 0, 0, 0);
    __syncthreads();
  }

  const int crow = (lane >> 4) * 4, ccol = lane & 15;
  float bv[4];
#pragma unroll
  for (int j = 0; j < 4; ++j) bv[j] = bp[n0 + wn * 64 + j * 16 + ccol];
#pragma unroll
  for (int i = 0; i < 4; ++i)
#pragma unroll
    for (int j = 0; j < 4; ++j) {
      const size_t base =
          (size_t)(m0 + wm * 64 + i * 16 + crow) * N + (n0 + wn * 64 + j * 16 + ccol);
#pragma unroll
      for (int jj = 0; jj < 4; ++jj)
        C[base + (size_t)jj * N] = acc[i][j][jj] + bv[j];
    }
}

// ---------------------------------------------------------------------------
// FUSED producer-consumer kernel (r17 structure + consumer depth-2 chains).
//   WGs 0-223  : pipelined gemm_xw producers (4-buffer LDS, vmcnt(6)).
//   WGs 224-255: lstm consumer; MFMA chain depth 4 -> 2 (accA kf{0,1},
//                accB kf{2,3}; summed only for the selected tile) — cuts
//                ~120 cyc of exposed MFMA dependency per step.
// ---------------------------------------------------------------------------
__global__ __launch_bounds__(512) void fused_xw_lstm(
    const bf16* __restrict__ xb, const bf16* __restrict__ WiT,
    bf16* __restrict__ Wx, const float* __restrict__ bp,
    const float* __restrict__ R, bf16* __restrict__ h_all,
    unsigned int* flags) {
  __shared__ bf16 Ab[4][128 * 32];      // 32 KB: A, 4-deep
  __shared__ bf16 Bb[4][2][128 * 32];   // 64 KB: B per tile, 4-deep
  __shared__ __align__(16) unsigned short hl[2][4][144];

  const int bid = blockIdx.x;
  const int tid = threadIdx.x;

  if (bid < 224) {
    // ======================= producer: pipelined gemm_xw =====================
    const int lane = tid & 63;
    const int w8 = tid >> 6;       // 0..7
    const int ts = w8 >> 2;        // tile within pair
    const int w4 = w8 & 3;
    const int wm = w4 >> 1, wn = w4 & 1;
    const int rr = lane & 15, kb = (lane >> 4) * 8;
    const int crow = (lane >> 4) * 4, ccol = lane & 15;
    const int frow = 16 * w8 + (lane >> 2);
    const int fcol = (lane & 3) * 8;
    bf16* const Adst = &Ab[0][16 * w8 * 32];
    bf16* const B0dst = &Bb[0][0][16 * w8 * 32];
    bf16* const B1dst = &Bb[0][1][16 * w8 * 32];

    for (int pi = bid; pi < 2048; pi += 224) {
      const int tix0 = pi * 2;
      const int s = tix0 >> 9;
      const int rem = tix0 & 511;
      const int bn = rem >> 2, q0 = rem & 3;
      const int b = bn >> 3, n = bn & 7;
      const int m0 = (b * 8 + s) * 128;
      const int n0base = (n * 4 + q0) * 128;

      const bf16* Asrc = xb + (size_t)(m0 + frow) * 1024 + fcol;
      const bf16* B0src = WiT + (size_t)(n0base + frow) * 1024 + fcol;
      const bf16* B1src = B0src + (size_t)128 * 1024;

#define FILLCHUNK(BUF, KC)                                                   \
  do {                                                                       \
    const size_t go_ = (size_t)(KC) * 32;                                    \
    GLD16(Asrc + go_, Adst + (BUF) * 4096);                                  \
    GLD16(B0src + go_, B0dst + (BUF) * 8192);                                \
    GLD16(B1src + go_, B1dst + (BUF) * 8192);                                \
  } while (0)

      f32x4 acc[4][4] = {};

#define COMPUTECHUNK(BUF)                                                    \
  do {                                                                       \
    const bf16* Ap_ = &Ab[(BUF)][0];                                         \
    const bf16* Bp_ = &Bb[(BUF)][ts][0];                                     \
    short8v af[4], bfr[4];                                                   \
    _Pragma("unroll") for (int i2 = 0; i2 < 4; ++i2) {                       \
      af[i2]  = *(const short8v*)&Ap_[(wm * 64 + i2 * 16 + rr) * 32 + kb];   \
      bfr[i2] = *(const short8v*)&Bp_[(wn * 64 + i2 * 16 + rr) * 32 + kb];   \
    }                                                                        \
    _Pragma("unroll") for (int i2 = 0; i2 < 4; ++i2)                         \
      _Pragma("unroll") for (int j2 = 0; j2 < 4; ++j2)                       \
        acc[i2][j2] = __builtin_amdgcn_mfma_f32_16x16x32_bf16(               \
            af[i2], bfr[j2], acc[i2][j2], 0, 0, 0);                          \
  } while (0)

      // prologue: chunks 0,1
      FILLCHUNK(0, 0);
      FILLCHUNK(1, 1);
      for (int i = 0; i < 30; ++i) {
        FILLCHUNK((i + 2) & 3, i + 2);
        VMW6();
        RAWBAR();
        COMPUTECHUNK(i & 3);
      }
      VMW3();
      RAWBAR();
      COMPUTECHUNK(2);  // i = 30
      VMW0();
      RAWBAR();
      COMPUTECHUNK(3);  // i = 31

      // epilogue: permuted-packed Wx (bias folded), coalesced
      {
        const int n0t = n0base + ts * 128;
#pragma unroll
        for (int i = 0; i < 4; ++i)
#pragma unroll
          for (int j = 0; j < 4; ++j) {
            const int pc = n0t + wn * 64 + j * 16 + ccol;
            const int nn = pc >> 9, gd = pc & 511;
            const int g = gd & 3, dd = gd >> 2;
            const float bvj = bp[(g * 8 + nn) * 128 + dd];
#pragma unroll
            for (int jj = 0; jj < 4; ++jj) {
              const int row = m0 + wm * 64 + i * 16 + crow + jj;
              const int bb = row >> 10, t = row & 1023;
              const size_t idx = (((size_t)(bb * 8 + nn) << 10) + t) * 512 + gd;
              Wx[idx] = __float2bfloat16(acc[i][j][jj] + bvj);
            }
          }
      }
      // full drain (vmcnt(0) before s_barrier) - once per pair
      __syncthreads();
      if (tid == 0) {
        __threadfence();  // publish Wx beyond this XCD's L2
        __hip_atomic_fetch_add(&flags[bn * 8 + s], 2u,
                               __ATOMIC_RELEASE, __HIP_MEMORY_SCOPE_AGENT);
      }
    }
#undef FILLCHUNK
#undef COMPUTECHUNK
  } else {
    // ============ consumer: lstm (r17 + depth-2 MFMA chains) ============
    const int cid = bid - 224;
    const int n = cid & 7, bq = cid >> 3;
    const int w = tid >> 6, lane = tid & 63;
    const int lg = lane >> 4, lc = lane & 15;
    const int bloc = lc & 3;
    const int ci = lc >> 2;
    const int dsite = 16 * w + 4 * ci + lg;

    short8v Af[4][4];
#pragma unroll
    for (int tau = 0; tau < 4; ++tau) {
      const int gd = 64 * w + 16 * tau + lc;
      const int g = gd & 3, d = gd >> 2;
      const float* rbase = R + ((size_t)(g * 8 + n) * 128 + d) * 128;
#pragma unroll
      for (int kf = 0; kf < 4; ++kf) {
        const float* rp = rbase + 32 * kf + 8 * lg;
        const float4 r0 = *(const float4*)rp;
        const float4 r1 = *(const float4*)(rp + 4);
        short8v bv;
        bv[0] = (short)bfu(r0.x); bv[1] = (short)bfu(r0.y);
        bv[2] = (short)bfu(r0.z); bv[3] = (short)bfu(r0.w);
        bv[4] = (short)bfu(r1.x); bv[5] = (short)bfu(r1.y);
        bv[6] = (short)bfu(r1.z); bv[7] = (short)bfu(r1.w);
        Af[tau][kf] = bv;
      }
    }

    for (int i = tid; i < 4 * 144; i += 512) (&hl[0][0][0])[i] = 0;
    __syncthreads();

    const bf16* wxb =
        Wx + ((size_t)((bq * 4 + bloc) * 8 + n) << 10) * 512 + dsite * 4;
    bf16* hout = h_all + ((size_t)(bq * 4 + bloc) << 20) + n * 128 + dsite;

    float c = 0.f;

    for (int s = 0; s < 8; ++s) {
      if (tid == 0) {
#pragma unroll
        for (int j = 0; j < 4; ++j) {
          const int fidx = ((bq * 4 + j) * 8 + n) * 8 + s;
          while (__hip_atomic_load(&flags[fidx], __ATOMIC_RELAXED,
                                   __HIP_MEMORY_SCOPE_AGENT) < 4u)
            __builtin_amdgcn_s_sleep(2);
        }
        __threadfence();
      }
      __syncthreads();

      ushort4 wxr[4];
#pragma unroll
      for (int u = 0; u < 4; ++u)
        wxr[u] = *(const ushort4*)(wxb + (size_t)(s * 128 + u) * 512);

      const int tend = s * 128 + 128;
      for (int t0 = s * 128; t0 < tend; t0 += 4) {
#pragma unroll
        for (int u = 0; u < 4; ++u) {
          const int t = t0 + u;
          const unsigned short* hb = &hl[t & 1][0][0];
          short8v Bf[4];
#pragma unroll
          for (int kf = 0; kf < 4; ++kf)
            Bf[kf] = *(const short8v*)(hb + bloc * 144 + kf * 32 + lg * 8);

          const ushort4 wxc = wxr[u];  // capture before overwrite (r11 lesson)

          // depth-2 MFMA chains: accA gets kf{0,1}, accB gets kf{2,3}
          f32x4 accA[4], accB[4];
#pragma unroll
          for (int tau = 0; tau < 4; ++tau) {
            accA[tau][0] = 0.f; accA[tau][1] = 0.f;
            accA[tau][2] = 0.f; accA[tau][3] = 0.f;
            accB[tau][0] = 0.f; accB[tau][1] = 0.f;
            accB[tau][2] = 0.f; accB[tau][3] = 0.f;
          }
#pragma unroll
          for (int tau = 0; tau < 4; ++tau) {
            accA[tau] = __builtin_amdgcn_mfma_f32_16x16x32_bf16(
                Af[tau][0], Bf[0], accA[tau], 0, 0, 0);
            accB[tau] = __builtin_amdgcn_mfma_f32_16x16x32_bf16(
                Af[tau][2], Bf[2], accB[tau], 0, 0, 0);
          }
#pragma unroll
          for (int tau = 0; tau < 4; ++tau) {
            accA[tau] = __builtin_amdgcn_mfma_f32_16x16x32_bf16(
                Af[tau][1], Bf[1], accA[tau], 0, 0, 0);
            accB[tau] = __builtin_amdgcn_mfma_f32_16x16x32_bf16(
                Af[tau][3], Bf[3], accB[tau], 0, 0, 0);
          }

          {
            const int tp = (t + 4 < tend) ? (t + 4) : (tend - 1);
            wxr[u] = *(const ushort4*)(wxb + (size_t)tp * 512);
          }

          // select tile ci from BOTH halves, then sum + wx
#define SEL(ACC, J)                                                          \
  ((ci & 2) ? ((ci & 1) ? ACC[3][J] : ACC[2][J])                             \
            : ((ci & 1) ? ACC[1][J] : ACC[0][J]))
          float pre0 = SEL(accA, 0) + SEL(accB, 0) +
                       __uint_as_float((unsigned)wxc.x << 16);
          float pre1 = SEL(accA, 1) + SEL(accB, 1) +
                       __uint_as_float((unsigned)wxc.y << 16);
          float pre2 = SEL(accA, 2) + SEL(accB, 2) +
                       __uint_as_float((unsigned)wxc.z << 16);
          float pre3 = SEL(accA, 3) + SEL(accB, 3) +
                       __uint_as_float((unsigned)wxc.w << 16);
#undef SEL

          const float i_ = sigm(pre0);
          const float f_ = sigm(pre1);
          const float z_ = tanh_(pre2);
          const float o_ = sigm(pre3);
          c = f_ * c + i_ * z_;
          const float h = o_ * tanh_(c);
          const bf16 h16 = __float2bfloat16(h);

          hl[(t + 1) & 1][bloc][dsite] = ((const unsigned short*)&h16)[0];
          hout[(size_t)t << 10] = h16;

          __builtin_amdgcn_sched_barrier(0);
          asm volatile("s_waitcnt lgkmcnt(0)" ::: "memory");
          __builtin_amdgcn_sched_barrier(0);
          __builtin_amdgcn_s_barrier();
          __builtin_amdgcn_sched_barrier(0);
        }
      }
    }
  }
}

// ---------------------------------------------------------------------------
extern "C" void kernel_launch(void* const* d_in, const int* in_sizes, int n_in,
                              void* d_out, int out_size, void* d_ws, size_t ws_size,
                              hipStream_t stream) {
  const float* x_emb = (const float*)d_in[0];  // [16,1024,1024]
  const float* W_in  = (const float*)d_in[1];  // [1024,4096]
  const float* R     = (const float*)d_in[2];  // [4,8,128,128]
  const float* bias  = (const float*)d_in[3];  // [4,8,128]
  const float* W_prj = (const float*)d_in[4];  // [2048,1024]
  const float* b_prj = (const float*)d_in[5];  // [2048]

  char* ws = (char*)d_ws;
  bf16* xb  = (bf16*)ws;                               // 32 MB
  bf16* WiT = (bf16*)(ws + (size_t)M1 * K1 * 2);       //  8 MB (row-permuted)
  bf16* Wpb = WiT + (size_t)N1q * K1;                  //  4 MB
  bf16* H   = Wpb + (size_t)N2 * K2;                   // 32 MB
  unsigned int* flags = (unsigned int*)(ws + ((size_t)76 << 20));  // 4 KB
  bf16* Wx = (bf16*)d_out;  // 134 MB packed [(b*8+n)*1024+t][d*4+g]

  cast_f32_bf16<<<(M1 * K1 / 4 + 255) / 256, 256, 0, stream>>>(x_emb, xb, M1 * K1 / 4);
  transpose_cast_perm<<<dim3(N1q / 32, K1 / 32), 256, 0, stream>>>(W_in, WiT, K1, N1q);
  cast_f32_bf16<<<(N2 * K2 / 4 + 255) / 256, 256, 0, stream>>>(W_prj, Wpb, N2 * K2 / 4);
  zero_flags<<<4, 256, 0, stream>>>(flags);

  fused_xw_lstm<<<dim3(256), dim3(512), 0, stream>>>(xb, WiT, Wx, bias, R, H, flags);

  gemm_out<<<dim3(N2 / 128, M1 / 128), 256, 0, stream>>>(
      H, Wpb, (float*)d_out, b_prj, K2, N2);
}

// Round 21
// 754.906 us; speedup vs baseline: 1.0547x; 1.0547x over previous
//
#include <hip/hip_runtime.h>
#include <hip/hip_bf16.h>

#define DEV __device__ __forceinline__

using bf16 = __hip_bfloat16;
typedef __attribute__((ext_vector_type(8))) short short8v;  // 8 bf16 = 4 VGPRs
typedef __attribute__((ext_vector_type(4))) float f32x4;

constexpr int Bq = 16, Tq = 1024, Eq = 1024, Gq = 4, Nq = 8, Dq = 128, Vq = 2048;
constexpr int M1 = Bq * Tq;        // 16384
constexpr int N1q = Gq * Nq * Dq;  // 4096
constexpr int K1 = Eq;             // 1024
constexpr int K2 = Nq * Dq;        // 1024
constexpr int N2 = Vq;             // 2048

DEV unsigned short bfu(float x) {
  union { bf16 h; unsigned short u; } cv;
  cv.h = __float2bfloat16(x);
  return cv.u;
}

DEV float rcp_(float x) { return __builtin_amdgcn_rcpf(x); }
DEV float sigm(float x) { return rcp_(1.0f + __expf(-x)); }
DEV float tanh_(float x) { return fmaf(2.0f, rcp_(1.0f + __expf(-2.0f * x)), -1.0f); }

// async global->LDS, 16B per lane; LDS dest is wave-uniform base + lane*16
#define GLD16(gp, lp)                                                       \
  __builtin_amdgcn_global_load_lds(                                        \
      (const __attribute__((address_space(1))) void*)(gp),                 \
      (__attribute__((address_space(3))) void*)(lp), 16, 0, 0)

#define SBAR0() __builtin_amdgcn_sched_barrier(0)
#define RAWBAR()                                                            \
  do { SBAR0(); __builtin_amdgcn_s_barrier(); SBAR0(); } while (0)
#define VMW6() asm volatile("s_waitcnt vmcnt(6)" ::: "memory")
#define VMW3() asm volatile("s_waitcnt vmcnt(3)" ::: "memory")
#define VMW0() asm volatile("s_waitcnt vmcnt(0)" ::: "memory")

// ---------------------------------------------------------------------------
// Prep kernels
// ---------------------------------------------------------------------------
__global__ __launch_bounds__(256) void cast_f32_bf16(const float* __restrict__ s,
                                                     bf16* __restrict__ d, int n4) {
  const int i = blockIdx.x * 256 + threadIdx.x;
  if (i >= n4) return;
  const float4 v = ((const float4*)s)[i];
  ushort4 u;
  u.x = bfu(v.x); u.y = bfu(v.y); u.z = bfu(v.z); u.w = bfu(v.w);
  ((ushort4*)d)[i] = u;
}

// W_in[k][c] f32 (c = g*1024+n*128+dd) -> WiT_perm[n*512 + dd*4 + g][k] bf16.
__global__ __launch_bounds__(256) void transpose_cast_perm(const float* __restrict__ s,
                                                           bf16* __restrict__ d,
                                                           int SK, int SN) {
  __shared__ float t[32][33];
  const int n0 = blockIdx.x * 32, k0 = blockIdx.y * 32;
  const int tx = threadIdx.x & 31, ty = threadIdx.x >> 5;  // ty: 0..7
#pragma unroll
  for (int i = 0; i < 32; i += 8)
    t[ty + i][tx] = s[(size_t)(k0 + ty + i) * SN + n0 + tx];
  __syncthreads();
#pragma unroll
  for (int i = 0; i < 32; i += 8) {
    const int c = n0 + ty + i;
    const int g = c >> 10, n = (c >> 7) & 7, dd = c & 127;
    const int rp = n * 512 + dd * 4 + g;
    d[(size_t)rp * SK + k0 + tx] = __float2bfloat16(t[tx][ty + i]);
  }
}

__global__ __launch_bounds__(256) void zero_flags(unsigned int* __restrict__ f) {
  f[blockIdx.x * 256 + threadIdx.x] = 0u;
}

// ---------------------------------------------------------------------------
// Standalone bf16 MFMA GEMM (m97 structure) for the output projection:
// C[M,N] f32 = A[M,K] @ Bt[N,K]^T + bias.  (multi-WG/CU co-residency hides
// the per-K-step barrier drain — do NOT fold this into a 1-WG/CU kernel.)
// ---------------------------------------------------------------------------
__global__ __launch_bounds__(256) void gemm_out(const bf16* __restrict__ A,
                                                const bf16* __restrict__ Bt,
                                                float* __restrict__ C,
                                                const float* __restrict__ bp,
                                                int K, int N) {
  __shared__ bf16 As[128 * 32];
  __shared__ bf16 Bs[128 * 32];
  const int m0 = blockIdx.y * 128, n0 = blockIdx.x * 128;
  const int tid = threadIdx.x;
  const int lane = tid & 63, w = tid >> 6;
  const int wm = w >> 1, wn = w & 1;

  const int srow = lane >> 2, scol = (lane & 3) * 8;
  const int ca = w * 2;
  const bf16* Ag0 = A + (size_t)(m0 + ca * 16 + srow) * K + scol;
  const bf16* Ag1 = Ag0 + (size_t)16 * K;
  const bf16* Bg0 = Bt + (size_t)(n0 + ca * 16 + srow) * K + scol;
  const bf16* Bg1 = Bg0 + (size_t)16 * K;
  bf16* Al0 = As + ca * 512;
  bf16* Al1 = Al0 + 512;
  bf16* Bl0 = Bs + ca * 512;
  bf16* Bl1 = Bl0 + 512;

  f32x4 acc[4][4] = {};
  const int rr = lane & 15;
  const int kb = (lane >> 4) * 8;

  for (int k0 = 0; k0 < K; k0 += 32) {
    GLD16(Ag0 + k0, Al0);
    GLD16(Ag1 + k0, Al1);
    GLD16(Bg0 + k0, Bl0);
    GLD16(Bg1 + k0, Bl1);
    __syncthreads();
    short8v af[4], bfr[4];
#pragma unroll
    for (int i = 0; i < 4; ++i) {
      af[i]  = *(const short8v*)&As[(wm * 64 + i * 16 + rr) * 32 + kb];
      bfr[i] = *(const short8v*)&Bs[(wn * 64 + i * 16 + rr) * 32 + kb];
    }
#pragma unroll
    for (int i = 0; i < 4; ++i)
#pragma unroll
      for (int j = 0; j < 4; ++j)
        acc[i][j] = __builtin_amdgcn_mfma_f32_16x16x32_bf16(af[i], bfr[j], acc[i][j], 0, 0, 0);
    __syncthreads();
  }

  const int crow = (lane >> 4) * 4, ccol = lane & 15;
  float bv[4];
#pragma unroll
  for (int j = 0; j < 4; ++j) bv[j] = bp[n0 + wn * 64 + j * 16 + ccol];
#pragma unroll
  for (int i = 0; i < 4; ++i)
#pragma unroll
    for (int j = 0; j < 4; ++j) {
      const size_t base =
          (size_t)(m0 + wm * 64 + i * 16 + crow) * N + (n0 + wn * 64 + j * 16 + ccol);
#pragma unroll
      for (int jj = 0; jj < 4; ++jj)
        C[base + (size_t)jj * N] = acc[i][j][jj] + bv[j];
    }
}

// ---------------------------------------------------------------------------
// FUSED producer-consumer kernel (r17 structure + all-WG chunk-0 pass).
//   Pass 0: ALL 256 WGs produce one pair (pi = bid) -> chunk 0 (tix 0..511)
//           complete after one pair (~25us) instead of ~2 passes (~50us).
//   WGs 0-223  : continue as producers, pi = 256+bid+224k, k=0..7 (exact
//                partition of the remaining 1792 pairs).
//   WGs 224-255: switch to the r17 lstm consumer (depth-4 chains — the
//                depth-2 variant of r20 regressed and is reverted).
// ---------------------------------------------------------------------------
__global__ __launch_bounds__(512) void fused_xw_lstm(
    const bf16* __restrict__ xb, const bf16* __restrict__ WiT,
    bf16* __restrict__ Wx, const float* __restrict__ bp,
    const float* __restrict__ R, bf16* __restrict__ h_all,
    unsigned int* flags) {
  __shared__ bf16 Ab[4][128 * 32];      // 32 KB: A, 4-deep
  __shared__ bf16 Bb[4][2][128 * 32];   // 64 KB: B per tile, 4-deep
  __shared__ __align__(16) unsigned short hl[2][4][144];

  const int bid = blockIdx.x;
  const int tid = threadIdx.x;

  // ---------------- shared producer-pair body (r17, byte-equivalent) -------
  auto produce_pair = [&](int pi) {
    const int lane = tid & 63;
    const int w8 = tid >> 6;
    const int ts = w8 >> 2;
    const int w4 = w8 & 3;
    const int wm = w4 >> 1, wn = w4 & 1;
    const int rr = lane & 15, kb = (lane >> 4) * 8;
    const int crow = (lane >> 4) * 4, ccol = lane & 15;
    const int frow = 16 * w8 + (lane >> 2);
    const int fcol = (lane & 3) * 8;
    bf16* const Adst = &Ab[0][16 * w8 * 32];
    bf16* const B0dst = &Bb[0][0][16 * w8 * 32];
    bf16* const B1dst = &Bb[0][1][16 * w8 * 32];

    const int tix0 = pi * 2;
    const int s = tix0 >> 9;
    const int rem = tix0 & 511;
    const int bn = rem >> 2, q0 = rem & 3;
    const int b = bn >> 3, n = bn & 7;
    const int m0 = (b * 8 + s) * 128;
    const int n0base = (n * 4 + q0) * 128;

    const bf16* Asrc = xb + (size_t)(m0 + frow) * 1024 + fcol;
    const bf16* B0src = WiT + (size_t)(n0base + frow) * 1024 + fcol;
    const bf16* B1src = B0src + (size_t)128 * 1024;

#define FILLCHUNK(BUF, KC)                                                   \
  do {                                                                       \
    const size_t go_ = (size_t)(KC) * 32;                                    \
    GLD16(Asrc + go_, Adst + (BUF) * 4096);                                  \
    GLD16(B0src + go_, B0dst + (BUF) * 8192);                                \
    GLD16(B1src + go_, B1dst + (BUF) * 8192);                                \
  } while (0)

    f32x4 acc[4][4] = {};

#define COMPUTECHUNK(BUF)                                                    \
  do {                                                                       \
    const bf16* Ap_ = &Ab[(BUF)][0];                                         \
    const bf16* Bp_ = &Bb[(BUF)][ts][0];                                     \
    short8v af[4], bfr[4];                                                   \
    _Pragma("unroll") for (int i2 = 0; i2 < 4; ++i2) {                       \
      af[i2]  = *(const short8v*)&Ap_[(wm * 64 + i2 * 16 + rr) * 32 + kb];   \
      bfr[i2] = *(const short8v*)&Bp_[(wn * 64 + i2 * 16 + rr) * 32 + kb];   \
    }                                                                        \
    _Pragma("unroll") for (int i2 = 0; i2 < 4; ++i2)                         \
      _Pragma("unroll") for (int j2 = 0; j2 < 4; ++j2)                       \
        acc[i2][j2] = __builtin_amdgcn_mfma_f32_16x16x32_bf16(               \
            af[i2], bfr[j2], acc[i2][j2], 0, 0, 0);                          \
  } while (0)

    FILLCHUNK(0, 0);
    FILLCHUNK(1, 1);
    for (int i = 0; i < 30; ++i) {
      FILLCHUNK((i + 2) & 3, i + 2);
      VMW6();
      RAWBAR();
      COMPUTECHUNK(i & 3);
    }
    VMW3();
    RAWBAR();
    COMPUTECHUNK(2);
    VMW0();
    RAWBAR();
    COMPUTECHUNK(3);

    // epilogue: permuted-packed Wx (bias folded), coalesced
    {
      const int n0t = n0base + ts * 128;
#pragma unroll
      for (int i = 0; i < 4; ++i)
#pragma unroll
        for (int j = 0; j < 4; ++j) {
          const int pc = n0t + wn * 64 + j * 16 + ccol;
          const int nn = pc >> 9, gd = pc & 511;
          const int g = gd & 3, dd = gd >> 2;
          const float bvj = bp[(g * 8 + nn) * 128 + dd];
#pragma unroll
          for (int jj = 0; jj < 4; ++jj) {
            const int row = m0 + wm * 64 + i * 16 + crow + jj;
            const int bb = row >> 10, t = row & 1023;
            const size_t idx = (((size_t)(bb * 8 + nn) << 10) + t) * 512 + gd;
            Wx[idx] = __float2bfloat16(acc[i][j][jj] + bvj);
          }
        }
    }
    __syncthreads();  // drains all waves' stores (vmcnt 0 before barrier)
    if (tid == 0) {
      __threadfence();  // publish Wx beyond this XCD's L2
      __hip_atomic_fetch_add(&flags[bn * 8 + s], 2u,
                             __ATOMIC_RELEASE, __HIP_MEMORY_SCOPE_AGENT);
    }
#undef FILLCHUNK
#undef COMPUTECHUNK
  };

  // ---------------- pass 0: every WG produces one chunk-0 pair -------------
  produce_pair(bid);

  if (bid < 224) {
    // ======================= producers continue =======================
    for (int pi = 256 + bid; pi < 2048; pi += 224) produce_pair(pi);
  } else {
    // ============ consumer: lstm (r17, depth-4 chains) ============
    const int cid = bid - 224;
    const int n = cid & 7, bq = cid >> 3;
    const int w = tid >> 6, lane = tid & 63;
    const int lg = lane >> 4, lc = lane & 15;
    const int bloc = lc & 3;
    const int ci = lc >> 2;
    const int dsite = 16 * w + 4 * ci + lg;

    short8v Af[4][4];
#pragma unroll
    for (int tau = 0; tau < 4; ++tau) {
      const int gd = 64 * w + 16 * tau + lc;
      const int g = gd & 3, d = gd >> 2;
      const float* rbase = R + ((size_t)(g * 8 + n) * 128 + d) * 128;
#pragma unroll
      for (int kf = 0; kf < 4; ++kf) {
        const float* rp = rbase + 32 * kf + 8 * lg;
        const float4 r0 = *(const float4*)rp;
        const float4 r1 = *(const float4*)(rp + 4);
        short8v bv;
        bv[0] = (short)bfu(r0.x); bv[1] = (short)bfu(r0.y);
        bv[2] = (short)bfu(r0.z); bv[3] = (short)bfu(r0.w);
        bv[4] = (short)bfu(r1.x); bv[5] = (short)bfu(r1.y);
        bv[6] = (short)bfu(r1.z); bv[7] = (short)bfu(r1.w);
        Af[tau][kf] = bv;
      }
    }

    for (int i = tid; i < 4 * 144; i += 512) (&hl[0][0][0])[i] = 0;
    __syncthreads();

    const bf16* wxb =
        Wx + ((size_t)((bq * 4 + bloc) * 8 + n) << 10) * 512 + dsite * 4;
    bf16* hout = h_all + ((size_t)(bq * 4 + bloc) << 20) + n * 128 + dsite;

    float c = 0.f;

    for (int s = 0; s < 8; ++s) {
      if (tid == 0) {
#pragma unroll
        for (int j = 0; j < 4; ++j) {
          const int fidx = ((bq * 4 + j) * 8 + n) * 8 + s;
          while (__hip_atomic_load(&flags[fidx], __ATOMIC_RELAXED,
                                   __HIP_MEMORY_SCOPE_AGENT) < 4u)
            __builtin_amdgcn_s_sleep(2);
        }
        __threadfence();
      }
      __syncthreads();

      ushort4 wxr[4];
#pragma unroll
      for (int u = 0; u < 4; ++u)
        wxr[u] = *(const ushort4*)(wxb + (size_t)(s * 128 + u) * 512);

      const int tend = s * 128 + 128;
      for (int t0 = s * 128; t0 < tend; t0 += 4) {
#pragma unroll
        for (int u = 0; u < 4; ++u) {
          const int t = t0 + u;
          const unsigned short* hb = &hl[t & 1][0][0];
          short8v Bf[4];
#pragma unroll
          for (int kf = 0; kf < 4; ++kf)
            Bf[kf] = *(const short8v*)(hb + bloc * 144 + kf * 32 + lg * 8);

          const ushort4 wxc = wxr[u];  // capture before overwrite (r11 lesson)

          f32x4 acc[4];
#pragma unroll
          for (int tau = 0; tau < 4; ++tau) {
            acc[tau][0] = 0.f; acc[tau][1] = 0.f;
            acc[tau][2] = 0.f; acc[tau][3] = 0.f;
          }
#pragma unroll
          for (int kf = 0; kf < 4; ++kf)
#pragma unroll
            for (int tau = 0; tau < 4; ++tau)
              acc[tau] = __builtin_amdgcn_mfma_f32_16x16x32_bf16(
                  Af[tau][kf], Bf[kf], acc[tau], 0, 0, 0);

          {
            const int tp = (t + 4 < tend) ? (t + 4) : (tend - 1);
            wxr[u] = *(const ushort4*)(wxb + (size_t)tp * 512);
          }

          float pre0 = (ci & 2) ? ((ci & 1) ? acc[3][0] : acc[2][0])
                                : ((ci & 1) ? acc[1][0] : acc[0][0]);
          float pre1 = (ci & 2) ? ((ci & 1) ? acc[3][1] : acc[2][1])
                                : ((ci & 1) ? acc[1][1] : acc[0][1]);
          float pre2 = (ci & 2) ? ((ci & 1) ? acc[3][2] : acc[2][2])
                                : ((ci & 1) ? acc[1][2] : acc[0][2]);
          float pre3 = (ci & 2) ? ((ci & 1) ? acc[3][3] : acc[2][3])
                                : ((ci & 1) ? acc[1][3] : acc[0][3]);
          pre0 += __uint_as_float((unsigned)wxc.x << 16);
          pre1 += __uint_as_float((unsigned)wxc.y << 16);
          pre2 += __uint_as_float((unsigned)wxc.z << 16);
          pre3 += __uint_as_float((unsigned)wxc.w << 16);

          const float i_ = sigm(pre0);
          const float f_ = sigm(pre1);
          const float z_ = tanh_(pre2);
          const float o_ = sigm(pre3);
          c = f_ * c + i_ * z_;
          const float h = o_ * tanh_(c);
          const bf16 h16 = __float2bfloat16(h);

          hl[(t + 1) & 1][bloc][dsite] = ((const unsigned short*)&h16)[0];
          hout[(size_t)t << 10] = h16;

          __builtin_amdgcn_sched_barrier(0);
          asm volatile("s_waitcnt lgkmcnt(0)" ::: "memory");
          __builtin_amdgcn_sched_barrier(0);
          __builtin_amdgcn_s_barrier();
          __builtin_amdgcn_sched_barrier(0);
        }
      }
    }
  }
}

// ---------------------------------------------------------------------------
extern "C" void kernel_launch(void* const* d_in, const int* in_sizes, int n_in,
                              void* d_out, int out_size, void* d_ws, size_t ws_size,
                              hipStream_t stream) {
  const float* x_emb = (const float*)d_in[0];  // [16,1024,1024]
  const float* W_in  = (const float*)d_in[1];  // [1024,4096]
  const float* R     = (const float*)d_in[2];  // [4,8,128,128]
  const float* bias  = (const float*)d_in[3];  // [4,8,128]
  const float* W_prj = (const float*)d_in[4];  // [2048,1024]
  const float* b_prj = (const float*)d_in[5];  // [2048]

  char* ws = (char*)d_ws;
  bf16* xb  = (bf16*)ws;                               // 32 MB
  bf16* WiT = (bf16*)(ws + (size_t)M1 * K1 * 2);       //  8 MB (row-permuted)
  bf16* Wpb = WiT + (size_t)N1q * K1;                  //  4 MB
  bf16* H   = Wpb + (size_t)N2 * K2;                   // 32 MB
  unsigned int* flags = (unsigned int*)(ws + ((size_t)76 << 20));  // 4 KB
  bf16* Wx = (bf16*)d_out;  // 134 MB packed [(b*8+n)*1024+t][d*4+g]

  cast_f32_bf16<<<(M1 * K1 / 4 + 255) / 256, 256, 0, stream>>>(x_emb, xb, M1 * K1 / 4);
  transpose_cast_perm<<<dim3(N1q / 32, K1 / 32), 256, 0, stream>>>(W_in, WiT, K1, N1q);
  cast_f32_bf16<<<(N2 * K2 / 4 + 255) / 256, 256, 0, stream>>>(W_prj, Wpb, N2 * K2 / 4);
  zero_flags<<<4, 256, 0, stream>>>(flags);

  fused_xw_lstm<<<dim3(256), dim3(512), 0, stream>>>(xb, WiT, Wx, bias, R, H, flags);

  gemm_out<<<dim3(N2 / 128, M1 / 128), 256, 0, stream>>>(
      H, Wpb, (float*)d_out, b_prj, K2, N2);
}